// Round 9
// baseline (673.935 us; speedup 1.0000x reference)
//
#include <hip/hip_runtime.h>
#include <hip/hip_bf16.h>

#define NTOK   4096
#define DMODEL 1024
#define DFF    4096
#define NEXP   8
#define TOPK   2
#define BM 256
#define BN 256
#define BK 64
#define NSLOT   (NTOK*TOPK)            // 8192
#define MAXSLOT (NSLOT + NEXP*BM)      // 10240
#define MAXTILE (MAXSLOT/BM)           // 40 = 8 XCDs * 5

typedef __attribute__((ext_vector_type(8))) short bf16x8;
typedef __attribute__((ext_vector_type(8))) unsigned short u16x8;
typedef __attribute__((ext_vector_type(4))) float f32x4;

__device__ __forceinline__ unsigned short f2bf(float f){
    union { float f; unsigned int u; } v; v.f = f;
    unsigned int r = (v.u + 0x7fffu + ((v.u >> 16) & 1u)) >> 16;
    return (unsigned short)r;
}

__device__ __forceinline__ void gload16(const unsigned short* g, unsigned short* l){
    __builtin_amdgcn_global_load_lds(
        (const __attribute__((address_space(1))) void*)g,
        (__attribute__((address_space(3))) void*)l,
        16, 0, 0);
}

#define MFMA16(a,b,c) __builtin_amdgcn_mfma_f32_16x16x32_bf16(a,b,c,0,0,0)

// ------ merged fp32 [R][C] -> bf16 [C][R] transpose-convert, fp32 LDS (conflict-free) ------
__global__ __launch_bounds__(256) void k_transpose_convert2(const float* __restrict__ W1,
                                                            const float* __restrict__ W2,
                                                            unsigned short* __restrict__ W1t,
                                                            unsigned short* __restrict__ W2t)
{
    __shared__ float tile[64][65];
    int z = blockIdx.z;
    const float* src; unsigned short* dst; int R, C, r0, c0;
    if(z < 8){
        src = W1  + (size_t)z * DMODEL * DFF;
        dst = W1t + (size_t)z * DMODEL * DFF;
        R = DMODEL; C = DFF;
        r0 = blockIdx.y * 64; c0 = blockIdx.x * 64;
    } else {
        src = W2  + (size_t)(z-8) * DFF * DMODEL;
        dst = W2t + (size_t)(z-8) * DFF * DMODEL;
        R = DFF; C = DMODEL;
        r0 = blockIdx.x * 64; c0 = blockIdx.y * 64;
    }
    int t = threadIdx.x;
    int tr  = t >> 4;          // 0..15
    int tc4 = (t & 15) * 4;    // 0..60
    #pragma unroll
    for(int i=0;i<4;i++){
        float4 v = *(const float4*)&src[(size_t)(r0 + tr + i*16)*C + c0 + tc4];
        tile[tc4+0][tr + i*16] = v.x;   // banks: (4*(t&15)+q+tr) mod 32 -> 2-way, free
        tile[tc4+1][tr + i*16] = v.y;
        tile[tc4+2][tr + i*16] = v.z;
        tile[tc4+3][tr + i*16] = v.w;
    }
    __syncthreads();
    int cr = t >> 3;           // 0..31
    int rb = (t & 7) * 8;      // 0..56
    #pragma unroll
    for(int i=0;i<2;i++){
        int c = cr + i*32;
        u16x8 o;
        #pragma unroll
        for(int q=0;q<8;q++) o[q] = f2bf(tile[c][rb + q]);   // (cr+8*(t&7)) mod 32 -> 2-way
        *(u16x8*)&dst[(size_t)(c0 + c)*R + r0 + rb] = o;
    }
}

// ---------------- gating (+ fused x fp32->bf16 convert) ----------------
__global__ __launch_bounds__(256) void k_gate(const float* __restrict__ x,
                                              const float* __restrict__ Wg,
                                              const float* __restrict__ bg,
                                              unsigned short* __restrict__ Xb,
                                              int* __restrict__ token_e,
                                              float* __restrict__ token_w,
                                              int* __restrict__ cnt)
{
    int tid = threadIdx.x;
    const float4* xs = (const float4*)x + (size_t)blockIdx.x * 1024;
    ushort4* xd = (ushort4*)Xb + (size_t)blockIdx.x * 1024;
    #pragma unroll
    for(int rep=0;rep<4;rep++){
        float4 v = xs[rep*256 + tid];
        ushort4 o; o.x=f2bf(v.x); o.y=f2bf(v.y); o.z=f2bf(v.z); o.w=f2bf(v.w);
        xd[rep*256 + tid] = o;
    }

    int wid = tid >> 6, lane = tid & 63;
    int t = blockIdx.x * 4 + wid;
    const float* xr = x + (size_t)t * DMODEL;
    float pe[NEXP];
    #pragma unroll
    for(int e=0;e<NEXP;e++) pe[e] = 0.f;
    for(int i=0;i<DMODEL/64;i++){
        int d = i*64 + lane;
        float xv = xr[d];
        const float* wr = Wg + (size_t)d * NEXP;
        #pragma unroll
        for(int e=0;e<NEXP;e++) pe[e] += xv * wr[e];
    }
    #pragma unroll
    for(int off=32; off>0; off>>=1){
        #pragma unroll
        for(int e=0;e<NEXP;e++) pe[e] += __shfl_xor(pe[e], off);
    }
    if(lane == 0){
        float lg[NEXP], mx = -1e30f;
        #pragma unroll
        for(int e=0;e<NEXP;e++){ lg[e] = pe[e] + bg[e]; mx = fmaxf(mx, lg[e]); }
        float pr[NEXP];
        #pragma unroll
        for(int e=0;e<NEXP;e++) pr[e] = expf(lg[e] - mx);
        int e0 = 0; float p0 = pr[0];
        #pragma unroll
        for(int e=1;e<NEXP;e++) if(pr[e] > p0){ p0 = pr[e]; e0 = e; }
        int e1 = -1; float p1 = -1.f;
        #pragma unroll
        for(int e=0;e<NEXP;e++) if(e != e0 && pr[e] > p1){ p1 = pr[e]; e1 = e; }
        float dn = p0 + p1;
        token_e[2*t]   = e0; token_w[2*t]   = p0/dn;
        token_e[2*t+1] = e1; token_w[2*t+1] = p1/dn;
        atomicAdd(&cnt[e0], 1); atomicAdd(&cnt[e1], 1);
    }
}

// ---------------- prefix + tile table + pad-fill + scatter (one block) ----------------
__global__ __launch_bounds__(256) void k_prefix_scatter(const int* __restrict__ cnt,
                                                        const int* __restrict__ token_e,
                                                        const float* __restrict__ token_w,
                                                        int* __restrict__ tile_e,
                                                        int* __restrict__ tile_row0,
                                                        int* __restrict__ tile_valid,
                                                        int* __restrict__ slot_token,
                                                        float* __restrict__ slot_w)
{
    __shared__ int sb[NEXP], scur[NEXP];
    int tid = threadIdx.x;
    if(tid == 0){
        int off = 0, nt = 0;
        for(int e=0;e<NEXP;e++){
            sb[e] = off; scur[e] = 0;
            int c = cnt[e];
            for(int r=0;r<c;r+=BM){
                tile_e[nt] = e; tile_row0[nt] = off + r;
                tile_valid[nt] = (c - r < BM) ? (c - r) : BM;
                nt++;
            }
            off += ((c + BM - 1)/BM)*BM;
        }
        for(int i=nt;i<MAXTILE;i++){ tile_e[i]=0; tile_row0[i]=0; tile_valid[i]=0; }
    }
    for(int s=tid; s<MAXSLOT; s+=256) slot_token[s] = 0;  // safe gather addr for pad rows
    __syncthreads();
    for(int i=tid; i<NSLOT; i+=256){
        int e = token_e[i];
        int s = sb[e] + atomicAdd(&scur[e], 1);
        slot_token[s] = i >> 1;
        slot_w[s] = token_w[i];
    }
}

// ---------------- grouped GEMM: 256x256 tile, 8 waves, R5-proven simple loop ----------------
// Same 2-barrier K-loop + gload_lds + XOR swizzle as the measured-best 128^2 kernel;
// only the tile is 4x bigger (4x FLOPs & bytes per synchronization, 4x fewer K-steps).
// A: bf16 row stride lda. GATHER: row via slot_token. B: bf16 [E][N][lda].
// GELU: OutH[slot][N] = gelu(acc+bias). else: atomicAdd into outF[token][col] of
// slot_w*(acc + (kbase==0 ? bias : 0)) — fused combine + free K-split (blockIdx.z).
template<bool GATHER, bool GELU>
__global__ __launch_bounds__(512, 2) void k_gemm(const unsigned short* __restrict__ A,
                                                 const unsigned short* __restrict__ Bw,
                                                 const float* __restrict__ bias,
                                                 const int* __restrict__ tile_e,
                                                 const int* __restrict__ tile_row0,
                                                 const int* __restrict__ tile_valid,
                                                 const int* __restrict__ slot_token,
                                                 const float* __restrict__ slot_w,
                                                 unsigned short* __restrict__ OutH,
                                                 float* __restrict__ outF,
                                                 int lda, int N, int klen)
{
    int xb = blockIdx.x;
    int tid = (xb & 7) * (MAXTILE/8) + (xb >> 3);   // XCD-chunked bijective swizzle (40 = 8*5)
    int valid = tile_valid[tid];
    if(valid == 0) return;
    int e = tile_e[tid];
    int row0 = tile_row0[tid];
    int n0 = blockIdx.y * BN;
    int kbase = blockIdx.z * klen;
    const unsigned short* Be = Bw + (size_t)e * N * lda;

    __shared__ unsigned short As[BM*BK];   // 32 KB
    __shared__ unsigned short Bs[BN*BK];   // 32 KB

    int t = threadIdx.x;                   // 0..511
    int lane = t & 63;
    int wid = t >> 6;                      // 0..7
    int wm = wid >> 2, wn = wid & 3;       // 2M x 4N wave grid; wave tile 128x64

    // staging: issue i stages row r = i*64 + (t>>3), phys chunk t&7;
    // source chunk = (t&7) ^ (r&7)  (r&7 == (t>>3)&7 since 64 ≡ 0 mod 8)
    int srow = t >> 3;                     // 0..63
    int csw  = (t & 7) ^ (srow & 7);
    const unsigned short* arow[4];
    const unsigned short* brow[4];
    #pragma unroll
    for(int i=0;i<4;i++){
        int r = i*64 + srow;
        size_t aoff;
        if(GATHER) aoff = (size_t)slot_token[row0 + r] * (size_t)lda;
        else       aoff = (size_t)(row0 + r) * (size_t)lda;
        arow[i] = A  + aoff + kbase + csw*8;
        brow[i] = Be + (size_t)(n0 + r)*lda + kbase + csw*8;
    }
    unsigned short* alds = As + (size_t)t * 8;
    unsigned short* blds = Bs + (size_t)t * 8;

    f32x4 acc[8][4];
    #pragma unroll
    for(int m=0;m<8;m++)
        #pragma unroll
        for(int n=0;n<4;n++)
            acc[m][n] = (f32x4){0.f,0.f,0.f,0.f};

    int rl = lane & 15;
    int g  = lane >> 4;
    int rx = rl & 7;

    for(int k0=0;k0<klen;k0+=BK){
        __syncthreads();   // previous compute done before LDS overwrite
        #pragma unroll
        for(int i=0;i<4;i++){
            gload16(arow[i] + k0, alds + i*4096);
            gload16(brow[i] + k0, blds + i*4096);
        }
        __syncthreads();   // compiler drains vmcnt(0) before barrier -> tile ready

        #pragma unroll
        for(int kb=0;kb<2;kb++){
            int sw = ((kb*4 + g) ^ rx) * 8;   // proven conflict-free swizzled chunk offset
            bf16x8 bfv[4];
            #pragma unroll
            for(int n=0;n<4;n++) bfv[n] = *(const bf16x8*)&Bs[(wn*64 + n*16 + rl)*BK + sw];
            #pragma unroll
            for(int mh=0;mh<2;mh++){          // M-half split caps live fragments
                bf16x8 af[4];
                #pragma unroll
                for(int m=0;m<4;m++) af[m] = *(const bf16x8*)&As[(wm*128 + mh*64 + m*16 + rl)*BK + sw];
                #pragma unroll
                for(int m=0;m<4;m++)
                    #pragma unroll
                    for(int n=0;n<4;n++)
                        acc[mh*4+m][n] = MFMA16(af[m], bfv[n], acc[mh*4+m][n]);
            }
        }
    }

    const float* be = bias + (size_t)e * N;
    #pragma unroll
    for(int mi=0;mi<8;mi++){
        int rb = wm*128 + mi*16 + g*4;
        #pragma unroll
        for(int j=0;j<4;j++){
            int r = rb + j;
            if(r >= valid) continue;
            size_t grow = (size_t)(row0 + r);
            if(GELU){
                #pragma unroll
                for(int n=0;n<4;n++){
                    int col = n0 + wn*64 + n*16 + rl;
                    float v = acc[mi][n][j] + be[col];
                    v = 0.5f * v * (1.f + erff(v * 0.70710678118654752f));
                    OutH[grow * (size_t)N + col] = f2bf(v);
                }
            } else {
                float wsc = slot_w[grow];
                float* orow = outF + (size_t)slot_token[grow] * DMODEL;
                #pragma unroll
                for(int n=0;n<4;n++){
                    int col = n0 + wn*64 + n*16 + rl;
                    float bterm = (kbase == 0) ? be[col] : 0.f;
                    float v = (acc[mi][n][j] + bterm) * wsc;
                    atomicAdd(&orow[col], v);
                }
            }
        }
    }
}

extern "C" void kernel_launch(void* const* d_in, const int* in_sizes, int n_in,
                              void* d_out, int out_size, void* d_ws, size_t ws_size,
                              hipStream_t stream)
{
    const float* x  = (const float*)d_in[0];
    const float* W1 = (const float*)d_in[1];
    const float* b1 = (const float*)d_in[2];
    const float* W2 = (const float*)d_in[3];
    const float* b2 = (const float*)d_in[4];
    const float* Wg = (const float*)d_in[5];
    const float* bg = (const float*)d_in[6];
    float* out = (float*)d_out;

    char* p = (char*)d_ws;
    auto alloc = [&](size_t bytes)->char*{
        char* r = p; p += (bytes + 255) & ~(size_t)255; return r;
    };
    unsigned short* W1t = (unsigned short*)alloc((size_t)NEXP*DFF*DMODEL*2);   // [E][DFF][DMODEL]
    unsigned short* W2t = (unsigned short*)alloc((size_t)NEXP*DMODEL*DFF*2);   // [E][DMODEL][DFF]
    unsigned short* Xb  = (unsigned short*)alloc((size_t)NTOK*DMODEL*2);
    unsigned short* H   = (unsigned short*)alloc((size_t)MAXSLOT*DFF*2);
    int*   slot_token = (int*)alloc(MAXSLOT*4);
    float* slot_w     = (float*)alloc(MAXSLOT*4);
    int*   token_e    = (int*)alloc(NSLOT*4);
    float* token_w    = (float*)alloc(NSLOT*4);
    int*   cnt        = (int*)alloc(32);
    int*   tile_e     = (int*)alloc(MAXTILE*4);
    int*   tile_row0  = (int*)alloc(MAXTILE*4);
    int*   tile_valid = (int*)alloc(MAXTILE*4);
    (void)ws_size; (void)in_sizes; (void)n_in; (void)out_size;

    hipMemsetAsync(cnt, 0, 32, stream);
    hipMemsetAsync(out, 0, (size_t)NTOK*DMODEL*4, stream);   // fused-combine accumulator base
    k_gate<<<NTOK/4, 256, 0, stream>>>(x, Wg, bg, Xb, token_e, token_w, cnt);
    k_transpose_convert2<<<dim3(DFF/64, DMODEL/64, 16), 256, 0, stream>>>(W1, W2, W1t, W2t);
    k_prefix_scatter<<<1, 256, 0, stream>>>(cnt, token_e, token_w,
                                            tile_e, tile_row0, tile_valid,
                                            slot_token, slot_w);
    // GEMM1: X[slot gather] x W1t -> H (gelu).  grid 40 x 16, K=1024
    k_gemm<true, true ><<<dim3(MAXTILE, DFF/BN, 1),    512, 0, stream>>>(
        Xb, W1t, b1, tile_e, tile_row0, tile_valid, slot_token, slot_w, H, nullptr,
        DMODEL, DFF, DMODEL);
    // GEMM2: H x W2t -> out (atomic combine), K-split x2.  grid 40 x 4 x 2, klen=2048
    k_gemm<false,false><<<dim3(MAXTILE, DMODEL/BN, 2), 512, 0, stream>>>(
        H,  W2t, b2, tile_e, tile_row0, tile_valid, slot_token, slot_w, nullptr, out,
        DFF, DMODEL, DFF/2);
}

// Round 10
// 586.617 us; speedup vs baseline: 1.1489x; 1.1489x over previous
//
#include <hip/hip_runtime.h>
#include <hip/hip_bf16.h>

#define NTOK   4096
#define DMODEL 1024
#define DFF    4096
#define NEXP   8
#define TOPK   2
#define BM 128
#define BN 128
#define BK 64
#define NSLOT   (NTOK*TOPK)            // 8192
#define MAXSLOT (NSLOT + NEXP*BM)      // 9216
#define MAXTILE (MAXSLOT/BM)           // 72 = 8 XCDs * 9

typedef __attribute__((ext_vector_type(8))) short bf16x8;
typedef __attribute__((ext_vector_type(8))) unsigned short u16x8;
typedef __attribute__((ext_vector_type(4))) float f32x4;

__device__ __forceinline__ unsigned short f2bf(float f){
    union { float f; unsigned int u; } v; v.f = f;
    unsigned int r = (v.u + 0x7fffu + ((v.u >> 16) & 1u)) >> 16;
    return (unsigned short)r;
}

__device__ __forceinline__ void gload16(const unsigned short* g, unsigned short* l){
    __builtin_amdgcn_global_load_lds(
        (const __attribute__((address_space(1))) void*)g,
        (__attribute__((address_space(3))) void*)l,
        16, 0, 0);
}

#define MFMA16(a,b,c) __builtin_amdgcn_mfma_f32_16x16x32_bf16(a,b,c,0,0,0)

// ------ merged fp32 [R][C] -> bf16 [C][R] transpose-convert, fp32 LDS (R9-proven, fast) ------
__global__ __launch_bounds__(256) void k_transpose_convert2(const float* __restrict__ W1,
                                                            const float* __restrict__ W2,
                                                            unsigned short* __restrict__ W1t,
                                                            unsigned short* __restrict__ W2t)
{
    __shared__ float tile[64][65];
    int z = blockIdx.z;
    const float* src; unsigned short* dst; int R, C, r0, c0;
    if(z < 8){
        src = W1  + (size_t)z * DMODEL * DFF;
        dst = W1t + (size_t)z * DMODEL * DFF;
        R = DMODEL; C = DFF;
        r0 = blockIdx.y * 64; c0 = blockIdx.x * 64;
    } else {
        src = W2  + (size_t)(z-8) * DFF * DMODEL;
        dst = W2t + (size_t)(z-8) * DFF * DMODEL;
        R = DFF; C = DMODEL;
        r0 = blockIdx.x * 64; c0 = blockIdx.y * 64;
    }
    int t = threadIdx.x;
    int tr  = t >> 4;          // 0..15
    int tc4 = (t & 15) * 4;    // 0..60
    #pragma unroll
    for(int i=0;i<4;i++){
        float4 v = *(const float4*)&src[(size_t)(r0 + tr + i*16)*C + c0 + tc4];
        tile[tc4+0][tr + i*16] = v.x;
        tile[tc4+1][tr + i*16] = v.y;
        tile[tc4+2][tr + i*16] = v.z;
        tile[tc4+3][tr + i*16] = v.w;
    }
    __syncthreads();
    int cr = t >> 3;           // 0..31
    int rb = (t & 7) * 8;      // 0..56
    #pragma unroll
    for(int i=0;i<2;i++){
        int c = cr + i*32;
        u16x8 o;
        #pragma unroll
        for(int q=0;q<8;q++) o[q] = f2bf(tile[c][rb + q]);
        *(u16x8*)&dst[(size_t)(c0 + c)*R + r0 + rb] = o;
    }
}

// ---------------- gating (+ fused x fp32->bf16 convert) ----------------
__global__ __launch_bounds__(256) void k_gate(const float* __restrict__ x,
                                              const float* __restrict__ Wg,
                                              const float* __restrict__ bg,
                                              unsigned short* __restrict__ Xb,
                                              int* __restrict__ token_e,
                                              float* __restrict__ token_w,
                                              int* __restrict__ cnt)
{
    int tid = threadIdx.x;
    const float4* xs = (const float4*)x + (size_t)blockIdx.x * 1024;
    ushort4* xd = (ushort4*)Xb + (size_t)blockIdx.x * 1024;
    #pragma unroll
    for(int rep=0;rep<4;rep++){
        float4 v = xs[rep*256 + tid];
        ushort4 o; o.x=f2bf(v.x); o.y=f2bf(v.y); o.z=f2bf(v.z); o.w=f2bf(v.w);
        xd[rep*256 + tid] = o;
    }

    int wid = tid >> 6, lane = tid & 63;
    int t = blockIdx.x * 4 + wid;
    const float* xr = x + (size_t)t * DMODEL;
    float pe[NEXP];
    #pragma unroll
    for(int e=0;e<NEXP;e++) pe[e] = 0.f;
    for(int i=0;i<DMODEL/64;i++){
        int d = i*64 + lane;
        float xv = xr[d];
        const float* wr = Wg + (size_t)d * NEXP;
        #pragma unroll
        for(int e=0;e<NEXP;e++) pe[e] += xv * wr[e];
    }
    #pragma unroll
    for(int off=32; off>0; off>>=1){
        #pragma unroll
        for(int e=0;e<NEXP;e++) pe[e] += __shfl_xor(pe[e], off);
    }
    if(lane == 0){
        float lg[NEXP], mx = -1e30f;
        #pragma unroll
        for(int e=0;e<NEXP;e++){ lg[e] = pe[e] + bg[e]; mx = fmaxf(mx, lg[e]); }
        float pr[NEXP];
        #pragma unroll
        for(int e=0;e<NEXP;e++) pr[e] = expf(lg[e] - mx);
        int e0 = 0; float p0 = pr[0];
        #pragma unroll
        for(int e=1;e<NEXP;e++) if(pr[e] > p0){ p0 = pr[e]; e0 = e; }
        int e1 = -1; float p1 = -1.f;
        #pragma unroll
        for(int e=0;e<NEXP;e++) if(e != e0 && pr[e] > p1){ p1 = pr[e]; e1 = e; }
        float dn = p0 + p1;
        token_e[2*t]   = e0; token_w[2*t]   = p0/dn;
        token_e[2*t+1] = e1; token_w[2*t+1] = p1/dn;
        atomicAdd(&cnt[e0], 1); atomicAdd(&cnt[e1], 1);
    }
}

// ---------------- prefix + tile table + pad-fill + scatter (one block) ----------------
__global__ __launch_bounds__(256) void k_prefix_scatter(const int* __restrict__ cnt,
                                                        const int* __restrict__ token_e,
                                                        const float* __restrict__ token_w,
                                                        int* __restrict__ tile_e,
                                                        int* __restrict__ tile_row0,
                                                        int* __restrict__ tile_valid,
                                                        int* __restrict__ slot_token,
                                                        float* __restrict__ slot_w)
{
    __shared__ int sb[NEXP], scur[NEXP];
    int tid = threadIdx.x;
    if(tid == 0){
        int off = 0, nt = 0;
        for(int e=0;e<NEXP;e++){
            sb[e] = off; scur[e] = 0;
            int c = cnt[e];
            for(int r=0;r<c;r+=BM){
                tile_e[nt] = e; tile_row0[nt] = off + r;
                tile_valid[nt] = (c - r < BM) ? (c - r) : BM;
                nt++;
            }
            off += ((c + BM - 1)/BM)*BM;
        }
        for(int i=nt;i<MAXTILE;i++){ tile_e[i]=0; tile_row0[i]=0; tile_valid[i]=0; }
    }
    for(int s=tid; s<MAXSLOT; s+=256) slot_token[s] = 0;  // safe gather addr for pad rows
    __syncthreads();
    for(int i=tid; i<NSLOT; i+=256){
        int e = token_e[i];
        int s = sb[e] + atomicAdd(&scur[e], 1);
        slot_token[s] = i >> 1;
        slot_w[s] = token_w[i];
    }
}

// ---------------- grouped GEMM: 128x128 tile, TWO waves (wave tile 128x64) ----------------
// Same proven 2-barrier K-loop + gload_lds + XOR swizzle as R8's best (140us) kernel.
// Changes vs R8: 2-wave blocks (finer sync domain, -25% LDS fragment traffic:
// each wave reads A full-height 128 + its B half 64 -> 24 KB/wave/step vs 16KBx4),
// ~4 blocks/CU overlap slots, optional K-split via blockIdx.z (atomic epilogue).
template<bool GATHER, bool GELU>
__global__ __launch_bounds__(128, 2) void k_gemm(const unsigned short* __restrict__ A,
                                                 const unsigned short* __restrict__ Bw,
                                                 const float* __restrict__ bias,
                                                 const int* __restrict__ tile_e,
                                                 const int* __restrict__ tile_row0,
                                                 const int* __restrict__ tile_valid,
                                                 const int* __restrict__ slot_token,
                                                 const float* __restrict__ slot_w,
                                                 unsigned short* __restrict__ OutH,
                                                 float* __restrict__ outF,
                                                 int lda, int N, int klen)
{
    int xb = blockIdx.x;
    int tid = (xb & 7) * (MAXTILE/8) + (xb >> 3);   // XCD-chunked bijective swizzle (72 = 8*9)
    int valid = tile_valid[tid];
    if(valid == 0) return;
    int e = tile_e[tid];
    int row0 = tile_row0[tid];
    int n0 = blockIdx.y * BN;
    int kbase = blockIdx.z * klen;
    const unsigned short* Be = Bw + (size_t)e * N * lda;

    __shared__ unsigned short As[BM*BK];   // 16 KB
    __shared__ unsigned short Bs[BN*BK];   // 16 KB

    int t = threadIdx.x;                   // 0..127
    int lane = t & 63;
    int w = t >> 6;                        // 0..1 : wave tile 128(M) x 64(N), N-half = w

    // staging: issue i (0..7) stages row r = i*16 + (t>>3), phys chunk t&7;
    // source chunk = (t&7) ^ (r&7)  (r&7 == (t>>3)&7 since 16 ≡ 0 mod 8)
    int srow = t >> 3;                     // 0..15
    int csw  = (t & 7) ^ (srow & 7);
    const unsigned short* arow[8];
    const unsigned short* brow[8];
    #pragma unroll
    for(int i=0;i<8;i++){
        int r = i*16 + srow;
        size_t aoff;
        if(GATHER) aoff = (size_t)slot_token[row0 + r] * (size_t)lda;
        else       aoff = (size_t)(row0 + r) * (size_t)lda;
        arow[i] = A  + aoff + kbase + csw*8;
        brow[i] = Be + (size_t)(n0 + r)*lda + kbase + csw*8;
    }

    f32x4 acc[8][4];
    #pragma unroll
    for(int m=0;m<8;m++)
        #pragma unroll
        for(int n=0;n<4;n++)
            acc[m][n] = (f32x4){0.f,0.f,0.f,0.f};

    int rl = lane & 15;
    int g  = lane >> 4;
    int rx = rl & 7;

    for(int k0=0;k0<klen;k0+=BK){
        __syncthreads();   // previous compute done before LDS overwrite
        #pragma unroll
        for(int i=0;i<8;i++){
            gload16(arow[i] + k0, As + i*1024 + t*8);
            gload16(brow[i] + k0, Bs + i*1024 + t*8);
        }
        __syncthreads();   // compiler drains vmcnt(0) before barrier -> tile ready

        #pragma unroll
        for(int kb=0;kb<2;kb++){
            int sw = ((kb*4 + g) ^ rx) * 8;   // proven conflict-free swizzled chunk offset
            bf16x8 bfv[4];
            #pragma unroll
            for(int n=0;n<4;n++) bfv[n] = *(const bf16x8*)&Bs[(w*64 + n*16 + rl)*BK + sw];
            #pragma unroll
            for(int mh=0;mh<2;mh++){          // M-half split caps live A fragments
                bf16x8 af[4];
                #pragma unroll
                for(int m=0;m<4;m++) af[m] = *(const bf16x8*)&As[(mh*64 + m*16 + rl)*BK + sw];
                #pragma unroll
                for(int m=0;m<4;m++)
                    #pragma unroll
                    for(int n=0;n<4;n++)
                        acc[mh*4+m][n] = MFMA16(af[m], bfv[n], acc[mh*4+m][n]);
            }
        }
    }

    const float* be = bias + (size_t)e * N;
    #pragma unroll
    for(int mi=0;mi<8;mi++){
        int rb = mi*16 + g*4;
        #pragma unroll
        for(int j=0;j<4;j++){
            int r = rb + j;
            if(r >= valid) continue;
            size_t grow = (size_t)(row0 + r);
            if(GELU){
                #pragma unroll
                for(int n=0;n<4;n++){
                    int col = n0 + w*64 + n*16 + rl;
                    float v = acc[mi][n][j] + be[col];
                    v = 0.5f * v * (1.f + erff(v * 0.70710678118654752f));
                    OutH[grow * (size_t)N + col] = f2bf(v);
                }
            } else {
                float wsc = slot_w[grow];
                float* orow = outF + (size_t)slot_token[grow] * DMODEL;
                #pragma unroll
                for(int n=0;n<4;n++){
                    int col = n0 + w*64 + n*16 + rl;
                    float bterm = (kbase == 0) ? be[col] : 0.f;
                    float v = (acc[mi][n][j] + bterm) * wsc;
                    atomicAdd(&orow[col], v);
                }
            }
        }
    }
}

extern "C" void kernel_launch(void* const* d_in, const int* in_sizes, int n_in,
                              void* d_out, int out_size, void* d_ws, size_t ws_size,
                              hipStream_t stream)
{
    const float* x  = (const float*)d_in[0];
    const float* W1 = (const float*)d_in[1];
    const float* b1 = (const float*)d_in[2];
    const float* W2 = (const float*)d_in[3];
    const float* b2 = (const float*)d_in[4];
    const float* Wg = (const float*)d_in[5];
    const float* bg = (const float*)d_in[6];
    float* out = (float*)d_out;

    char* p = (char*)d_ws;
    auto alloc = [&](size_t bytes)->char*{
        char* r = p; p += (bytes + 255) & ~(size_t)255; return r;
    };
    unsigned short* W1t = (unsigned short*)alloc((size_t)NEXP*DFF*DMODEL*2);   // [E][DFF][DMODEL]
    unsigned short* W2t = (unsigned short*)alloc((size_t)NEXP*DMODEL*DFF*2);   // [E][DMODEL][DFF]
    unsigned short* Xb  = (unsigned short*)alloc((size_t)NTOK*DMODEL*2);
    unsigned short* H   = (unsigned short*)alloc((size_t)MAXSLOT*DFF*2);
    int*   slot_token = (int*)alloc(MAXSLOT*4);
    float* slot_w     = (float*)alloc(MAXSLOT*4);
    int*   token_e    = (int*)alloc(NSLOT*4);
    float* token_w    = (float*)alloc(NSLOT*4);
    int*   cnt        = (int*)alloc(32);
    int*   tile_e     = (int*)alloc(MAXTILE*4);
    int*   tile_row0  = (int*)alloc(MAXTILE*4);
    int*   tile_valid = (int*)alloc(MAXTILE*4);
    (void)ws_size; (void)in_sizes; (void)n_in; (void)out_size;

    hipMemsetAsync(cnt, 0, 32, stream);
    hipMemsetAsync(out, 0, (size_t)NTOK*DMODEL*4, stream);   // fused-combine accumulator base
    k_gate<<<NTOK/4, 256, 0, stream>>>(x, Wg, bg, Xb, token_e, token_w, cnt);
    k_transpose_convert2<<<dim3(DFF/64, DMODEL/64, 16), 256, 0, stream>>>(W1, W2, W1t, W2t);
    k_prefix_scatter<<<1, 256, 0, stream>>>(cnt, token_e, token_w,
                                            tile_e, tile_row0, tile_valid,
                                            slot_token, slot_w);
    // GEMM1: X[slot gather] x W1t -> H (gelu).  grid 72 x 32, K=1024
    k_gemm<true, true ><<<dim3(MAXTILE, DFF/BN, 1),    128, 0, stream>>>(
        Xb, W1t, b1, tile_e, tile_row0, tile_valid, slot_token, slot_w, H, nullptr,
        DMODEL, DFF, DMODEL);
    // GEMM2: H x W2t -> out (atomic combine), K-split x2.  grid 72 x 8 x 2, klen=2048
    k_gemm<false,false><<<dim3(MAXTILE, DMODEL/BN, 2), 128, 0, stream>>>(
        H,  W2t, b2, tile_e, tile_row0, tile_valid, slot_token, slot_w, nullptr, out,
        DFF, DMODEL, DFF/2);
}

// Round 11
// 512.968 us; speedup vs baseline: 1.3138x; 1.1436x over previous
//
#include <hip/hip_runtime.h>
#include <hip/hip_bf16.h>

#define NTOK   4096
#define DMODEL 1024
#define DFF    4096
#define NEXP   8
#define TOPK   2
#define BM 128
#define BN 128
#define BK 64
#define NSLOT   (NTOK*TOPK)            // 8192
#define MAXSLOT (NSLOT + NEXP*BM)      // 9216
#define MAXTILE (MAXSLOT/BM)           // 72 = 8 XCDs * 9

typedef __attribute__((ext_vector_type(8))) short bf16x8;
typedef __attribute__((ext_vector_type(8))) unsigned short u16x8;
typedef __attribute__((ext_vector_type(4))) float f32x4;

__device__ __forceinline__ unsigned short f2bf(float f){
    union { float f; unsigned int u; } v; v.f = f;
    unsigned int r = (v.u + 0x7fffu + ((v.u >> 16) & 1u)) >> 16;
    return (unsigned short)r;
}

__device__ __forceinline__ void gload16(const unsigned short* g, unsigned short* l){
    __builtin_amdgcn_global_load_lds(
        (const __attribute__((address_space(1))) void*)g,
        (__attribute__((address_space(3))) void*)l,
        16, 0, 0);
}

// ------ merged fp32 [R][C] -> bf16 [C][R] transpose-convert, fp32 LDS (R9-proven) ------
__global__ __launch_bounds__(256) void k_transpose_convert2(const float* __restrict__ W1,
                                                            const float* __restrict__ W2,
                                                            unsigned short* __restrict__ W1t,
                                                            unsigned short* __restrict__ W2t)
{
    __shared__ float tile[64][65];
    int z = blockIdx.z;
    const float* src; unsigned short* dst; int R, C, r0, c0;
    if(z < 8){
        src = W1  + (size_t)z * DMODEL * DFF;
        dst = W1t + (size_t)z * DMODEL * DFF;
        R = DMODEL; C = DFF;
        r0 = blockIdx.y * 64; c0 = blockIdx.x * 64;
    } else {
        src = W2  + (size_t)(z-8) * DFF * DMODEL;
        dst = W2t + (size_t)(z-8) * DFF * DMODEL;
        R = DFF; C = DMODEL;
        r0 = blockIdx.x * 64; c0 = blockIdx.y * 64;
    }
    int t = threadIdx.x;
    int tr  = t >> 4;          // 0..15
    int tc4 = (t & 15) * 4;    // 0..60
    #pragma unroll
    for(int i=0;i<4;i++){
        float4 v = *(const float4*)&src[(size_t)(r0 + tr + i*16)*C + c0 + tc4];
        tile[tc4+0][tr + i*16] = v.x;
        tile[tc4+1][tr + i*16] = v.y;
        tile[tc4+2][tr + i*16] = v.z;
        tile[tc4+3][tr + i*16] = v.w;
    }
    __syncthreads();
    int cr = t >> 3;           // 0..31
    int rb = (t & 7) * 8;      // 0..56
    #pragma unroll
    for(int i=0;i<2;i++){
        int c = cr + i*32;
        u16x8 o;
        #pragma unroll
        for(int q=0;q<8;q++) o[q] = f2bf(tile[c][rb + q]);
        *(u16x8*)&dst[(size_t)(c0 + c)*R + r0 + rb] = o;
    }
}

// ---------------- gating (+ fused x fp32->bf16 convert) ----------------
__global__ __launch_bounds__(256) void k_gate(const float* __restrict__ x,
                                              const float* __restrict__ Wg,
                                              const float* __restrict__ bg,
                                              unsigned short* __restrict__ Xb,
                                              int* __restrict__ token_e,
                                              float* __restrict__ token_w,
                                              int* __restrict__ cnt)
{
    int tid = threadIdx.x;
    const float4* xs = (const float4*)x + (size_t)blockIdx.x * 1024;
    ushort4* xd = (ushort4*)Xb + (size_t)blockIdx.x * 1024;
    #pragma unroll
    for(int rep=0;rep<4;rep++){
        float4 v = xs[rep*256 + tid];
        ushort4 o; o.x=f2bf(v.x); o.y=f2bf(v.y); o.z=f2bf(v.z); o.w=f2bf(v.w);
        xd[rep*256 + tid] = o;
    }

    int wid = tid >> 6, lane = tid & 63;
    int t = blockIdx.x * 4 + wid;
    const float* xr = x + (size_t)t * DMODEL;
    float pe[NEXP];
    #pragma unroll
    for(int e=0;e<NEXP;e++) pe[e] = 0.f;
    for(int i=0;i<DMODEL/64;i++){
        int d = i*64 + lane;
        float xv = xr[d];
        const float* wr = Wg + (size_t)d * NEXP;
        #pragma unroll
        for(int e=0;e<NEXP;e++) pe[e] += xv * wr[e];
    }
    #pragma unroll
    for(int off=32; off>0; off>>=1){
        #pragma unroll
        for(int e=0;e<NEXP;e++) pe[e] += __shfl_xor(pe[e], off);
    }
    if(lane == 0){
        float lg[NEXP], mx = -1e30f;
        #pragma unroll
        for(int e=0;e<NEXP;e++){ lg[e] = pe[e] + bg[e]; mx = fmaxf(mx, lg[e]); }
        float pr[NEXP];
        #pragma unroll
        for(int e=0;e<NEXP;e++) pr[e] = expf(lg[e] - mx);
        int e0 = 0; float p0 = pr[0];
        #pragma unroll
        for(int e=1;e<NEXP;e++) if(pr[e] > p0){ p0 = pr[e]; e0 = e; }
        int e1 = -1; float p1 = -1.f;
        #pragma unroll
        for(int e=0;e<NEXP;e++) if(e != e0 && pr[e] > p1){ p1 = pr[e]; e1 = e; }
        float dn = p0 + p1;
        token_e[2*t]   = e0; token_w[2*t]   = p0/dn;
        token_e[2*t+1] = e1; token_w[2*t+1] = p1/dn;
        atomicAdd(&cnt[e0], 1); atomicAdd(&cnt[e1], 1);
    }
}

// ---------------- prefix + tile table + pad-fill + scatter (one block) ----------------
__global__ __launch_bounds__(256) void k_prefix_scatter(const int* __restrict__ cnt,
                                                        const int* __restrict__ token_e,
                                                        const float* __restrict__ token_w,
                                                        int* __restrict__ tile_e,
                                                        int* __restrict__ tile_row0,
                                                        int* __restrict__ tile_valid,
                                                        int* __restrict__ slot_token,
                                                        float* __restrict__ slot_w)
{
    __shared__ int sb[NEXP], scur[NEXP];
    int tid = threadIdx.x;
    if(tid == 0){
        int off = 0, nt = 0;
        for(int e=0;e<NEXP;e++){
            sb[e] = off; scur[e] = 0;
            int c = cnt[e];
            for(int r=0;r<c;r+=BM){
                tile_e[nt] = e; tile_row0[nt] = off + r;
                tile_valid[nt] = (c - r < BM) ? (c - r) : BM;
                nt++;
            }
            off += ((c + BM - 1)/BM)*BM;
        }
        for(int i=nt;i<MAXTILE;i++){ tile_e[i]=0; tile_row0[i]=0; tile_valid[i]=0; }
    }
    for(int s=tid; s<MAXSLOT; s+=256) slot_token[s] = 0;  // safe gather addr for pad rows
    __syncthreads();
    for(int i=tid; i<NSLOT; i+=256){
        int e = token_e[i];
        int s = sb[e] + atomicAdd(&scur[e], 1);
        slot_token[s] = i >> 1;
        slot_w[s] = token_w[i];
    }
}

// ---------------- grouped GEMM tile kernel (R8-proven structure, 4 blocks/CU, K-split) ----------------
// A: bf16, row stride lda. GATHER: A row r -> slot_token[row0+r]. else A row = row0+r.
// B: bf16 [E][N][lda] (pre-transposed).
// GELU: OutH[slot][N] = gelu(acc+bias).  else: atomicAdd fp32 into outF[token][col] of
// slot_w*(acc + (kbase==0 ? bias : 0)) — fused combine, K-split-safe.
template<bool GATHER, bool GELU>
__global__ __launch_bounds__(256, 4) void k_gemm(const unsigned short* __restrict__ A,
                                                 const unsigned short* __restrict__ Bw,
                                                 const float* __restrict__ bias,
                                                 const int* __restrict__ tile_e,
                                                 const int* __restrict__ tile_row0,
                                                 const int* __restrict__ tile_valid,
                                                 const int* __restrict__ slot_token,
                                                 const float* __restrict__ slot_w,
                                                 unsigned short* __restrict__ OutH,
                                                 float* __restrict__ outF,
                                                 int lda, int N, int klen)
{
    int xb = blockIdx.x;
    int tid = (xb & 7) * (MAXTILE/8) + (xb >> 3);   // XCD-chunked bijective swizzle (72 = 8*9)
    int valid = tile_valid[tid];
    if(valid == 0) return;
    int e = tile_e[tid];
    int row0 = tile_row0[tid];
    int n0 = blockIdx.y * BN;
    int kbase = blockIdx.z * klen;
    const unsigned short* Be = Bw + (size_t)e * N * lda;

    __shared__ unsigned short As[BM*BK];
    __shared__ unsigned short Bs[BN*BK];

    int t = threadIdx.x;
    int lane = t & 63;
    int wid = t >> 6;
    int wr = wid >> 1, wc = wid & 1;

    // staging: thread t, issue i stages LDS chunk p = i*256+t (16B chunks)
    // row r = i*32 + (t>>3), phys chunk c = t&7; content = global chunk c ^ (r&7)
    int srow = t >> 3;                      // 0..31
    int csw  = (t & 7) ^ (srow & 7);        // swizzled source chunk
    const unsigned short* arow[4];
    const unsigned short* brow[4];
    #pragma unroll
    for(int i=0;i<4;i++){
        int r = i*32 + srow;
        size_t aoff;
        if(GATHER) aoff = (size_t)slot_token[row0 + r] * (size_t)lda;
        else       aoff = (size_t)(row0 + r) * (size_t)lda;
        arow[i] = A  + aoff + kbase + csw*8;
        brow[i] = Be + (size_t)(n0 + r)*lda + kbase + csw*8;
    }
    unsigned short* alds = As + (size_t)t * 8;
    unsigned short* blds = Bs + (size_t)t * 8;

    f32x4 acc[4][4];
    #pragma unroll
    for(int m=0;m<4;m++)
        #pragma unroll
        for(int n=0;n<4;n++)
            acc[m][n] = (f32x4){0.f,0.f,0.f,0.f};

    int rl = lane & 15;
    int g  = lane >> 4;
    int rx = rl & 7;

    for(int k0=0;k0<klen;k0+=BK){
        __syncthreads();   // previous compute done before LDS overwrite
        #pragma unroll
        for(int i=0;i<4;i++){
            gload16(arow[i] + k0, alds + i*2048);
            gload16(brow[i] + k0, blds + i*2048);
        }
        __syncthreads();   // compiler drains vmcnt(0) before barrier -> tile ready

        #pragma unroll
        for(int kb=0;kb<2;kb++){
            int sw = ((kb*4 + g) ^ rx) * 8;   // proven conflict-free swizzled chunk offset
            bf16x8 af[4], bfv[4];
            #pragma unroll
            for(int m=0;m<4;m++) af[m]  = *(const bf16x8*)&As[(wr*64 + m*16 + rl)*BK + sw];
            #pragma unroll
            for(int n=0;n<4;n++) bfv[n] = *(const bf16x8*)&Bs[(wc*64 + n*16 + rl)*BK + sw];
            #pragma unroll
            for(int m=0;m<4;m++)
                #pragma unroll
                for(int n=0;n<4;n++)
                    acc[m][n] = __builtin_amdgcn_mfma_f32_16x16x32_bf16(af[m], bfv[n], acc[m][n], 0, 0, 0);
        }
    }

    const float* be = bias + (size_t)e * N;
    #pragma unroll
    for(int m=0;m<4;m++){
        int rb = wr*64 + m*16 + g*4;
        #pragma unroll
        for(int j=0;j<4;j++){
            int r = rb + j;
            if(r >= valid) continue;
            size_t grow = (size_t)(row0 + r);
            if(GELU){
                #pragma unroll
                for(int n=0;n<4;n++){
                    int col = n0 + wc*64 + n*16 + rl;
                    float v = acc[m][n][j] + be[col];
                    v = 0.5f * v * (1.f + erff(v * 0.70710678118654752f));
                    OutH[grow * (size_t)N + col] = f2bf(v);
                }
            } else {
                float wsc = slot_w[grow];
                float* orow = outF + (size_t)slot_token[grow] * DMODEL;
                #pragma unroll
                for(int n=0;n<4;n++){
                    int col = n0 + wc*64 + n*16 + rl;
                    float bterm = (kbase == 0) ? be[col] : 0.f;
                    float v = (acc[m][n][j] + bterm) * wsc;
                    atomicAdd(&orow[col], v);
                }
            }
        }
    }
}

extern "C" void kernel_launch(void* const* d_in, const int* in_sizes, int n_in,
                              void* d_out, int out_size, void* d_ws, size_t ws_size,
                              hipStream_t stream)
{
    const float* x  = (const float*)d_in[0];
    const float* W1 = (const float*)d_in[1];
    const float* b1 = (const float*)d_in[2];
    const float* W2 = (const float*)d_in[3];
    const float* b2 = (const float*)d_in[4];
    const float* Wg = (const float*)d_in[5];
    const float* bg = (const float*)d_in[6];
    float* out = (float*)d_out;

    char* p = (char*)d_ws;
    auto alloc = [&](size_t bytes)->char*{
        char* r = p; p += (bytes + 255) & ~(size_t)255; return r;
    };
    unsigned short* W1t = (unsigned short*)alloc((size_t)NEXP*DFF*DMODEL*2);   // [E][DFF][DMODEL]
    unsigned short* W2t = (unsigned short*)alloc((size_t)NEXP*DMODEL*DFF*2);   // [E][DMODEL][DFF]
    unsigned short* Xb  = (unsigned short*)alloc((size_t)NTOK*DMODEL*2);
    unsigned short* H   = (unsigned short*)alloc((size_t)MAXSLOT*DFF*2);
    int*   slot_token = (int*)alloc(MAXSLOT*4);
    float* slot_w     = (float*)alloc(MAXSLOT*4);
    int*   token_e    = (int*)alloc(NSLOT*4);
    float* token_w    = (float*)alloc(NSLOT*4);
    int*   cnt        = (int*)alloc(32);
    int*   tile_e     = (int*)alloc(MAXTILE*4);
    int*   tile_row0  = (int*)alloc(MAXTILE*4);
    int*   tile_valid = (int*)alloc(MAXTILE*4);
    (void)ws_size; (void)in_sizes; (void)n_in; (void)out_size;

    hipMemsetAsync(cnt, 0, 32, stream);
    hipMemsetAsync(out, 0, (size_t)NTOK*DMODEL*4, stream);   // fused-combine accumulator base
    k_gate<<<NTOK/4, 256, 0, stream>>>(x, Wg, bg, Xb, token_e, token_w, cnt);
    k_transpose_convert2<<<dim3(DFF/64, DMODEL/64, 16), 256, 0, stream>>>(W1, W2, W1t, W2t);
    k_prefix_scatter<<<1, 256, 0, stream>>>(cnt, token_e, token_w,
                                            tile_e, tile_row0, tile_valid,
                                            slot_token, slot_w);
    // GEMM1: X[slot gather] x W1t -> H (gelu).  grid 72 x 32, K=1024
    k_gemm<true, true ><<<dim3(MAXTILE, DFF/BN, 1),    256, 0, stream>>>(
        Xb, W1t, b1, tile_e, tile_row0, tile_valid, slot_token, slot_w, H, nullptr,
        DMODEL, DFF, DMODEL);
    // GEMM2: H x W2t -> out (atomic combine), K-split x2.  grid 72 x 8 x 2, klen=2048
    k_gemm<false,false><<<dim3(MAXTILE, DMODEL/BN, 2), 256, 0, stream>>>(
        H,  W2t, b2, tile_e, tile_row0, tile_valid, slot_token, slot_w, nullptr, out,
        DFF, DMODEL, DFF/2);
}

// Round 12
// 480.901 us; speedup vs baseline: 1.4014x; 1.0667x over previous
//
#include <hip/hip_runtime.h>
#include <hip/hip_bf16.h>

#define NTOK   4096
#define DMODEL 1024
#define DFF    4096
#define NEXP   8
#define TOPK   2
#define BM 128
#define BN 128
#define BK 64
#define NSLOT   (NTOK*TOPK)            // 8192
#define MAXSLOT (NSLOT + NEXP*BM)      // 9216
#define MAXTILE (MAXSLOT/BM)           // 72 = 8 XCDs * 9

typedef __attribute__((ext_vector_type(8))) short bf16x8;
typedef __attribute__((ext_vector_type(8))) unsigned short u16x8;
typedef __attribute__((ext_vector_type(4))) float f32x4;

__device__ __forceinline__ unsigned short f2bf(float f){
    union { float f; unsigned int u; } v; v.f = f;
    unsigned int r = (v.u + 0x7fffu + ((v.u >> 16) & 1u)) >> 16;
    return (unsigned short)r;
}

__device__ __forceinline__ void gload16(const unsigned short* g, unsigned short* l){
    __builtin_amdgcn_global_load_lds(
        (const __attribute__((address_space(1))) void*)g,
        (__attribute__((address_space(3))) void*)l,
        16, 0, 0);
}

// ------ merged fp32 [R][C] -> bf16 [C][R] transpose-convert, fp32 LDS (R9-proven) ------
__global__ __launch_bounds__(256) void k_transpose_convert2(const float* __restrict__ W1,
                                                            const float* __restrict__ W2,
                                                            unsigned short* __restrict__ W1t,
                                                            unsigned short* __restrict__ W2t)
{
    __shared__ float tile[64][65];
    int z = blockIdx.z;
    const float* src; unsigned short* dst; int R, C, r0, c0;
    if(z < 8){
        src = W1  + (size_t)z * DMODEL * DFF;
        dst = W1t + (size_t)z * DMODEL * DFF;
        R = DMODEL; C = DFF;
        r0 = blockIdx.y * 64; c0 = blockIdx.x * 64;
    } else {
        src = W2  + (size_t)(z-8) * DFF * DMODEL;
        dst = W2t + (size_t)(z-8) * DFF * DMODEL;
        R = DFF; C = DMODEL;
        r0 = blockIdx.x * 64; c0 = blockIdx.y * 64;
    }
    int t = threadIdx.x;
    int tr  = t >> 4;          // 0..15
    int tc4 = (t & 15) * 4;    // 0..60
    #pragma unroll
    for(int i=0;i<4;i++){
        float4 v = *(const float4*)&src[(size_t)(r0 + tr + i*16)*C + c0 + tc4];
        tile[tc4+0][tr + i*16] = v.x;
        tile[tc4+1][tr + i*16] = v.y;
        tile[tc4+2][tr + i*16] = v.z;
        tile[tc4+3][tr + i*16] = v.w;
    }
    __syncthreads();
    int cr = t >> 3;           // 0..31
    int rb = (t & 7) * 8;      // 0..56
    #pragma unroll
    for(int i=0;i<2;i++){
        int c = cr + i*32;
        u16x8 o;
        #pragma unroll
        for(int q=0;q<8;q++) o[q] = f2bf(tile[c][rb + q]);
        *(u16x8*)&dst[(size_t)(c0 + c)*R + r0 + rb] = o;
    }
}

// ---------------- gating (+ fused x fp32->bf16 convert) ----------------
__global__ __launch_bounds__(256) void k_gate(const float* __restrict__ x,
                                              const float* __restrict__ Wg,
                                              const float* __restrict__ bg,
                                              unsigned short* __restrict__ Xb,
                                              int* __restrict__ token_e,
                                              float* __restrict__ token_w,
                                              int* __restrict__ cnt)
{
    int tid = threadIdx.x;
    const float4* xs = (const float4*)x + (size_t)blockIdx.x * 1024;
    ushort4* xd = (ushort4*)Xb + (size_t)blockIdx.x * 1024;
    #pragma unroll
    for(int rep=0;rep<4;rep++){
        float4 v = xs[rep*256 + tid];
        ushort4 o; o.x=f2bf(v.x); o.y=f2bf(v.y); o.z=f2bf(v.z); o.w=f2bf(v.w);
        xd[rep*256 + tid] = o;
    }

    int wid = tid >> 6, lane = tid & 63;
    int t = blockIdx.x * 4 + wid;
    const float* xr = x + (size_t)t * DMODEL;
    float pe[NEXP];
    #pragma unroll
    for(int e=0;e<NEXP;e++) pe[e] = 0.f;
    for(int i=0;i<DMODEL/64;i++){
        int d = i*64 + lane;
        float xv = xr[d];
        const float* wr = Wg + (size_t)d * NEXP;
        #pragma unroll
        for(int e=0;e<NEXP;e++) pe[e] += xv * wr[e];
    }
    #pragma unroll
    for(int off=32; off>0; off>>=1){
        #pragma unroll
        for(int e=0;e<NEXP;e++) pe[e] += __shfl_xor(pe[e], off);
    }
    if(lane == 0){
        float lg[NEXP], mx = -1e30f;
        #pragma unroll
        for(int e=0;e<NEXP;e++){ lg[e] = pe[e] + bg[e]; mx = fmaxf(mx, lg[e]); }
        float pr[NEXP];
        #pragma unroll
        for(int e=0;e<NEXP;e++) pr[e] = expf(lg[e] - mx);
        int e0 = 0; float p0 = pr[0];
        #pragma unroll
        for(int e=1;e<NEXP;e++) if(pr[e] > p0){ p0 = pr[e]; e0 = e; }
        int e1 = -1; float p1 = -1.f;
        #pragma unroll
        for(int e=0;e<NEXP;e++) if(e != e0 && pr[e] > p1){ p1 = pr[e]; e1 = e; }
        float dn = p0 + p1;
        token_e[2*t]   = e0; token_w[2*t]   = p0/dn;
        token_e[2*t+1] = e1; token_w[2*t+1] = p1/dn;
        atomicAdd(&cnt[e0], 1); atomicAdd(&cnt[e1], 1);
    }
}

// ---------------- prefix + tile table + pad-fill + scatter (one block) ----------------
__global__ __launch_bounds__(256) void k_prefix_scatter(const int* __restrict__ cnt,
                                                        const int* __restrict__ token_e,
                                                        const float* __restrict__ token_w,
                                                        int* __restrict__ tile_e,
                                                        int* __restrict__ tile_row0,
                                                        int* __restrict__ tile_valid,
                                                        int* __restrict__ slot_token,
                                                        float* __restrict__ slot_w)
{
    __shared__ int sb[NEXP], scur[NEXP];
    int tid = threadIdx.x;
    if(tid == 0){
        int off = 0, nt = 0;
        for(int e=0;e<NEXP;e++){
            sb[e] = off; scur[e] = 0;
            int c = cnt[e];
            for(int r=0;r<c;r+=BM){
                tile_e[nt] = e; tile_row0[nt] = off + r;
                tile_valid[nt] = (c - r < BM) ? (c - r) : BM;
                nt++;
            }
            off += ((c + BM - 1)/BM)*BM;
        }
        for(int i=nt;i<MAXTILE;i++){ tile_e[i]=0; tile_row0[i]=0; tile_valid[i]=0; }
    }
    for(int s=tid; s<MAXSLOT; s+=256) slot_token[s] = 0;  // safe gather addr for pad rows
    __syncthreads();
    for(int i=tid; i<NSLOT; i+=256){
        int e = token_e[i];
        int s = sb[e] + atomicAdd(&scur[e], 1);
        slot_token[s] = i >> 1;
        slot_w[s] = token_w[i];
    }
}

// ---------------- grouped GEMM tile kernel (exact R8-measured-best configuration) ----------------
// A: bf16, lda == K. GATHER: A row r -> slot_token[row0+r]. else A row = row0+r.
// B: bf16 [E][N][K] (pre-transposed).
// GELU: OutH[slot][N] = gelu(acc+bias).  else: atomicAdd fp32 into outF[token][col] of
// slot_w*(acc+bias) — fused combine.
template<bool GATHER, bool GELU>
__global__ __launch_bounds__(256, 3) void k_gemm(const unsigned short* __restrict__ A,
                                                 const unsigned short* __restrict__ Bw,
                                                 const float* __restrict__ bias,
                                                 const int* __restrict__ tile_e,
                                                 const int* __restrict__ tile_row0,
                                                 const int* __restrict__ tile_valid,
                                                 const int* __restrict__ slot_token,
                                                 const float* __restrict__ slot_w,
                                                 unsigned short* __restrict__ OutH,
                                                 float* __restrict__ outF,
                                                 int K, int N)
{
    int xb = blockIdx.x;
    int tid = (xb & 7) * (MAXTILE/8) + (xb >> 3);   // XCD-chunked bijective swizzle (72 = 8*9)
    int valid = tile_valid[tid];
    if(valid == 0) return;
    int e = tile_e[tid];
    int row0 = tile_row0[tid];
    int n0 = blockIdx.y * BN;
    const unsigned short* Be = Bw + (size_t)e * N * K;

    __shared__ unsigned short As[BM*BK];
    __shared__ unsigned short Bs[BN*BK];

    int t = threadIdx.x;
    int lane = t & 63;
    int wid = t >> 6;
    int wr = wid >> 1, wc = wid & 1;

    // staging: thread t, issue i stages LDS chunk p = i*256+t (16B chunks)
    // row r = i*32 + (t>>3), phys chunk c = t&7; content = global chunk c ^ (r&7)
    int srow = t >> 3;                      // 0..31
    int csw  = (t & 7) ^ (srow & 7);        // swizzled source chunk
    const unsigned short* arow[4];
    const unsigned short* brow[4];
    #pragma unroll
    for(int i=0;i<4;i++){
        int r = i*32 + srow;
        size_t aoff;
        if(GATHER) aoff = (size_t)slot_token[row0 + r] * (size_t)K;
        else       aoff = (size_t)(row0 + r) * (size_t)K;
        arow[i] = A  + aoff + csw*8;
        brow[i] = Be + (size_t)(n0 + r)*K + csw*8;
    }
    unsigned short* alds = As + (size_t)t * 8;
    unsigned short* blds = Bs + (size_t)t * 8;

    f32x4 acc[4][4];
    #pragma unroll
    for(int m=0;m<4;m++)
        #pragma unroll
        for(int n=0;n<4;n++)
            acc[m][n] = (f32x4){0.f,0.f,0.f,0.f};

    int rl = lane & 15;
    int g  = lane >> 4;
    int rx = rl & 7;

    for(int k0=0;k0<K;k0+=BK){
        __syncthreads();   // previous compute done before LDS overwrite
        #pragma unroll
        for(int i=0;i<4;i++){
            gload16(arow[i] + k0, alds + i*2048);
            gload16(brow[i] + k0, blds + i*2048);
        }
        __syncthreads();   // compiler drains vmcnt(0) before barrier -> tile ready

        #pragma unroll
        for(int kb=0;kb<2;kb++){
            int sw = ((kb*4 + g) ^ rx) * 8;   // proven conflict-free swizzled chunk offset
            bf16x8 af[4], bfv[4];
            #pragma unroll
            for(int m=0;m<4;m++) af[m]  = *(const bf16x8*)&As[(wr*64 + m*16 + rl)*BK + sw];
            #pragma unroll
            for(int n=0;n<4;n++) bfv[n] = *(const bf16x8*)&Bs[(wc*64 + n*16 + rl)*BK + sw];
            #pragma unroll
            for(int m=0;m<4;m++)
                #pragma unroll
                for(int n=0;n<4;n++)
                    acc[m][n] = __builtin_amdgcn_mfma_f32_16x16x32_bf16(af[m], bfv[n], acc[m][n], 0, 0, 0);
        }
    }

    const float* be = bias + (size_t)e * N;
    #pragma unroll
    for(int m=0;m<4;m++){
        int rb = wr*64 + m*16 + g*4;
        #pragma unroll
        for(int j=0;j<4;j++){
            int r = rb + j;
            if(r >= valid) continue;
            size_t grow = (size_t)(row0 + r);
            if(GELU){
                #pragma unroll
                for(int n=0;n<4;n++){
                    int col = n0 + wc*64 + n*16 + rl;
                    float v = acc[m][n][j] + be[col];
                    v = 0.5f * v * (1.f + erff(v * 0.70710678118654752f));
                    OutH[grow * (size_t)N + col] = f2bf(v);
                }
            } else {
                float wsc = slot_w[grow];
                float* orow = outF + (size_t)slot_token[grow] * DMODEL;
                #pragma unroll
                for(int n=0;n<4;n++){
                    int col = n0 + wc*64 + n*16 + rl;
                    float v = (acc[m][n][j] + be[col]) * wsc;
                    atomicAdd(&orow[col], v);
                }
            }
        }
    }
}

extern "C" void kernel_launch(void* const* d_in, const int* in_sizes, int n_in,
                              void* d_out, int out_size, void* d_ws, size_t ws_size,
                              hipStream_t stream)
{
    const float* x  = (const float*)d_in[0];
    const float* W1 = (const float*)d_in[1];
    const float* b1 = (const float*)d_in[2];
    const float* W2 = (const float*)d_in[3];
    const float* b2 = (const float*)d_in[4];
    const float* Wg = (const float*)d_in[5];
    const float* bg = (const float*)d_in[6];
    float* out = (float*)d_out;

    char* p = (char*)d_ws;
    auto alloc = [&](size_t bytes)->char*{
        char* r = p; p += (bytes + 255) & ~(size_t)255; return r;
    };
    unsigned short* W1t = (unsigned short*)alloc((size_t)NEXP*DFF*DMODEL*2);   // [E][DFF][DMODEL]
    unsigned short* W2t = (unsigned short*)alloc((size_t)NEXP*DMODEL*DFF*2);   // [E][DMODEL][DFF]
    unsigned short* Xb  = (unsigned short*)alloc((size_t)NTOK*DMODEL*2);
    unsigned short* H   = (unsigned short*)alloc((size_t)MAXSLOT*DFF*2);
    int*   slot_token = (int*)alloc(MAXSLOT*4);
    float* slot_w     = (float*)alloc(MAXSLOT*4);
    int*   token_e    = (int*)alloc(NSLOT*4);
    float* token_w    = (float*)alloc(NSLOT*4);
    int*   cnt        = (int*)alloc(32);
    int*   tile_e     = (int*)alloc(MAXTILE*4);
    int*   tile_row0  = (int*)alloc(MAXTILE*4);
    int*   tile_valid = (int*)alloc(MAXTILE*4);
    (void)ws_size; (void)in_sizes; (void)n_in; (void)out_size;

    hipMemsetAsync(cnt, 0, 32, stream);
    hipMemsetAsync(out, 0, (size_t)NTOK*DMODEL*4, stream);   // fused-combine accumulator base
    k_gate<<<NTOK/4, 256, 0, stream>>>(x, Wg, bg, Xb, token_e, token_w, cnt);
    k_transpose_convert2<<<dim3(DFF/64, DMODEL/64, 16), 256, 0, stream>>>(W1, W2, W1t, W2t);
    k_prefix_scatter<<<1, 256, 0, stream>>>(cnt, token_e, token_w,
                                            tile_e, tile_row0, tile_valid,
                                            slot_token, slot_w);
    // GEMM1: X[slot gather] x W1t -> H (gelu).  grid 72 x 32, K=1024
    k_gemm<true, true ><<<dim3(MAXTILE, DFF/BN), 256, 0, stream>>>(
        Xb, W1t, b1, tile_e, tile_row0, tile_valid, slot_token, slot_w, H, nullptr,
        DMODEL, DFF);
    // GEMM2: H x W2t -> out (atomic fused combine).  grid 72 x 8, K=4096
    k_gemm<false,false><<<dim3(MAXTILE, DMODEL/BN), 256, 0, stream>>>(
        H,  W2t, b2, tile_e, tile_row0, tile_valid, slot_token, slot_w, nullptr, out,
        DFF, DMODEL);
}